// Round 1
// baseline (28.165 us; speedup 1.0000x reference)
//
#include <hip/hip_runtime.h>
#include <math.h>

// PhysicalHarmonicResonanceSystem:
//   idx = d % NP;  p = primes[idx]
//   freq = p * (phi*pi/D) * sigmoid(rscale[idx]) * E
//   angle = pshift[idx] + tm_b * 2*pi,  tm_b = (hash_b % 1000)/1000
//   spec[b,d] = freq * (1 + 0.1*sin(angle));  row-normalize to ||row|| = E
// Only NP=50 distinct values per row -> compute pattern once per block,
// replicate with vectorized float4 stores. Pure write-BW bound.

#define PHI_PI 5.083203692315259f  // ((1+sqrt(5))/2) * pi

__global__ __launch_bounds__(256) void phrs_kernel(
    const int*   __restrict__ token_hash,
    const int*   __restrict__ primes,
    const float* __restrict__ rscales,
    const float* __restrict__ pshifts,
    const float* __restrict__ energy,
    float*       __restrict__ out,
    int B, int D, int NP)
{
    __shared__ float  s_sn[64];    // raw s_j values (NP <= 64)
    __shared__ float4 s_pat[64];   // period pattern as float4 (PL <= 64)
    __shared__ float  s_inv;

    const int b   = blockIdx.x;
    const int tid = threadIdx.x;
    const float E = energy[0];

    // ---- per-row scalar setup: 50 distinct values ----
    if (tid < NP) {
        const float tm    = (float)(token_hash[b] % 1000) * 1e-3f;
        const float p     = (float)primes[tid];
        const float sig   = 1.0f / (1.0f + __expf(-rscales[tid]) * 0.0f + expf(-rscales[tid]) * 1.0f);
        const float freq  = p * (PHI_PI / (float)D) * sig * E;
        const float angle = pshifts[tid] + tm * 6.2831853071795864769f;
        s_sn[tid] = freq * (1.0f + 0.1f * sinf(angle));
    }
    __syncthreads();

    if (tid == 0) {
        // weighted sum of squares: cnt_j = D/NP + (j < D%NP)
        const int q = D / NP, r = D % NP;
        float acc = 0.0f;
        for (int j = 0; j < NP; ++j) {
            float v = s_sn[j];
            float cnt = (float)(q + (j < r ? 1 : 0));
            acc += cnt * v * v;
        }
        float norm = sqrtf(acc);
        s_inv = (norm > 0.0f) ? (E / norm) : 1.0f;
    }
    __syncthreads();

    const float inv = s_inv;

    if ((D & 3) == 0) {
        // pattern length in float4s: PL = NP / gcd(NP,4)
        int g = ((NP & 3) == 0) ? 4 : (((NP & 1) == 0) ? 2 : 1);
        const int PL = NP / g;
        for (int m = tid; m < PL; m += 256) {
            int e = 4 * m;
            float4 v;
            v.x = s_sn[(e    ) % NP] * inv;
            v.y = s_sn[(e + 1) % NP] * inv;
            v.z = s_sn[(e + 2) % NP] * inv;
            v.w = s_sn[(e + 3) % NP] * inv;
            s_pat[m] = v;
        }
        __syncthreads();

        // ---- replicate: coalesced float4 stores, k % PL tracked incrementally
        float4* __restrict__ out4 = reinterpret_cast<float4*>(out);
        const int nv = D >> 2;
        const size_t rowbase = (size_t)b * (size_t)nv;
        int rmod = tid % PL;
        const int step = 256 % PL;
        for (int k = tid; k < nv; k += 256) {
            out4[rowbase + k] = s_pat[rmod];
            rmod += step;
            if (rmod >= PL) rmod -= PL;
        }
    } else {
        // generic scalar fallback (not hit for D=8192)
        const size_t rowbase = (size_t)b * (size_t)D;
        for (int i = tid; i < D; i += 256) {
            out[rowbase + i] = s_sn[i % NP] * inv;
        }
    }
}

extern "C" void kernel_launch(void* const* d_in, const int* in_sizes, int n_in,
                              void* d_out, int out_size, void* d_ws, size_t ws_size,
                              hipStream_t stream) {
    const int*   token_hash = (const int*)  d_in[0];
    const int*   primes     = (const int*)  d_in[1];
    const float* rscales    = (const float*)d_in[2];
    const float* pshifts    = (const float*)d_in[3];
    const float* energy     = (const float*)d_in[4];
    float*       out        = (float*)      d_out;

    const int B  = in_sizes[0];
    const int NP = in_sizes[1];
    const int D  = out_size / B;

    phrs_kernel<<<dim3(B), dim3(256), 0, stream>>>(
        token_hash, primes, rscales, pshifts, energy, out, B, D, NP);
}

// Round 2
// 26.924 us; speedup vs baseline: 1.0461x; 1.0461x over previous
//
#include <hip/hip_runtime.h>
#include <math.h>

// PhysicalHarmonicResonanceSystem:
//   idx = d % NP;  p = primes[idx]
//   freq = p * (phi*pi/D) * sigmoid(rscale[idx]) * E
//   angle = pshift[idx] + tm_b * 2*pi,  tm_b = (hash_b % 1000)/1000
//   spec[b,d] = freq * (1 + 0.1*sin(angle));  row-normalize to ||row|| = E
//
// Only NP=50 distinct values per row. Round 1 (block-per-row, serial reduce)
// hit 4.77 TB/s vs 6.6 TB/s fill ceiling -> prelude-bound.
// Round 2: one ROW PER WAVE (4 rows / 256-block):
//   - prelude amortized over 32 store iters instead of 8
//   - serial thread-0 reduce -> 6-step __shfl_xor butterfly (all lanes busy)
//   - inv broadcast in-register; 2 barriers instead of 3

#define PHI_PI  5.083203692315259f   // ((1+sqrt(5))/2) * pi
#define TWO_PI  6.2831853071795864769f

__global__ __launch_bounds__(256) void phrs_kernel(
    const int*   __restrict__ token_hash,
    const int*   __restrict__ primes,
    const float* __restrict__ rscales,
    const float* __restrict__ pshifts,
    const float* __restrict__ energy,
    float*       __restrict__ out,
    int B, int D, int NP)
{
    __shared__ float  s_raw[4][64];   // raw s_j per wave (NP <= 64)
    __shared__ float4 s_pat[4][32];   // period-25 float4 pattern per wave

    const int w    = threadIdx.x >> 6;   // wave id in block (row owner)
    const int lane = threadIdx.x & 63;
    const int b    = blockIdx.x * 4 + w; // one row per wave
    const float E  = energy[0];

    // ---- per-row setup: lanes 0..NP-1 each compute one distinct value ----
    float red = 0.0f;
    if (b < B && lane < NP) {
        const float tm    = (float)(token_hash[b] % 1000) * 1e-3f;
        const float p     = (float)primes[lane];
        const float sig   = 1.0f / (1.0f + expf(-rscales[lane]));
        const float freq  = p * (PHI_PI / (float)D) * sig * E;
        const float angle = pshifts[lane] + tm * TWO_PI;
        const float s     = freq * (1.0f + 0.1f * sinf(angle));
        s_raw[w][lane] = s;
        // cnt_j = D/NP + (j < D%NP): weighted sum of squares for the norm
        const int q = D / NP, r = D % NP;
        red = (float)(q + (lane < r ? 1 : 0)) * s * s;
    }
    // butterfly reduce across the wave (lanes >= NP contribute 0)
    #pragma unroll
    for (int off = 32; off; off >>= 1)
        red += __shfl_xor(red, off, 64);
    const float inv = (red > 0.0f) ? (E / sqrtf(red)) : 1.0f;

    __syncthreads();

    if (NP == 50 && (D & 255) == 0) {
        // ---- build period-25 float4 pattern (covers 100 = lcm(50,4) elems) ----
        if (b < B && lane < 25) {
            const int e = 4 * lane;
            int i0 = e;     if (i0 >= 50) i0 -= 50;
            int i1 = e + 1; if (i1 >= 50) i1 -= 50;
            int i2 = e + 2; if (i2 >= 50) i2 -= 50;
            int i3 = e + 3; if (i3 >= 50) i3 -= 50;
            float4 v;
            v.x = s_raw[w][i0] * inv;
            v.y = s_raw[w][i1] * inv;
            v.z = s_raw[w][i2] * inv;
            v.w = s_raw[w][i3] * inv;
            s_pat[w][lane] = v;
        }
        __syncthreads();

        // ---- stream: 32 coalesced float4 stores per lane, k%25 incremental ----
        if (b < B) {
            float4* __restrict__ out4 = reinterpret_cast<float4*>(out);
            const int nv = D >> 2;
            const size_t base = (size_t)b * (size_t)nv;
            int rmod = lane;
            if (rmod >= 25) rmod -= 25;
            if (rmod >= 25) rmod -= 25;   // lane < 64 -> at most 2 subtracts
            const int step = 64 % 25;     // 14
            #pragma unroll 8
            for (int k = lane; k < nv; k += 64) {
                out4[base + k] = s_pat[w][rmod];
                rmod += step;
                if (rmod >= 25) rmod -= 25;
            }
        }
    } else {
        // generic scalar fallback (not hit for D=8192, NP=50)
        __syncthreads();
        if (b < B) {
            const size_t rowbase = (size_t)b * (size_t)D;
            for (int i = lane; i < D; i += 64)
                out[rowbase + i] = s_raw[w][i % NP] * inv;
        }
    }
}

extern "C" void kernel_launch(void* const* d_in, const int* in_sizes, int n_in,
                              void* d_out, int out_size, void* d_ws, size_t ws_size,
                              hipStream_t stream) {
    const int*   token_hash = (const int*)  d_in[0];
    const int*   primes     = (const int*)  d_in[1];
    const float* rscales    = (const float*)d_in[2];
    const float* pshifts    = (const float*)d_in[3];
    const float* energy     = (const float*)d_in[4];
    float*       out        = (float*)      d_out;

    const int B  = in_sizes[0];
    const int NP = in_sizes[1];
    const int D  = out_size / B;

    const int blocks = (B + 3) / 4;   // one row per wave, 4 waves per block
    phrs_kernel<<<dim3(blocks), dim3(256), 0, stream>>>(
        token_hash, primes, rscales, pshifts, energy, out, B, D, NP);
}